// Round 6
// baseline (451.353 us; speedup 1.0000x reference)
//
#include <hip/hip_runtime.h>
#include <hip/hip_bf16.h>

#define B_ 128
#define S_ 196
#define E_ 768
#define M_ 768
#define KTOT (S_*E_)      // 150528
#define KSPLIT 32
#define STEPS 147         // 32-k steps per slice: 150528/32/32
#define ZC 4              // z-chunks in reduce kernel

typedef __bf16 bf16x8 __attribute__((ext_vector_type(8)));
typedef float  f32x4  __attribute__((ext_vector_type(4)));

__device__ inline bf16x8 cvt8(const float* __restrict__ p) {
    float4 a = *(const float4*)p;
    float4 b = *(const float4*)(p + 4);
    bf16x8 r;
    r[0] = (__bf16)a.x; r[1] = (__bf16)a.y; r[2] = (__bf16)a.z; r[3] = (__bf16)a.w;
    r[4] = (__bf16)b.x; r[5] = (__bf16)b.y; r[6] = (__bf16)b.z; r[7] = (__bf16)b.w;
    return r;
}

__device__ inline bf16x8 cvt8v(float4 a, float4 b) {
    bf16x8 r;
    r[0] = (__bf16)a.x; r[1] = (__bf16)a.y; r[2] = (__bf16)a.z; r[3] = (__bf16)a.w;
    r[4] = (__bf16)b.x; r[5] = (__bf16)b.y; r[6] = (__bf16)b.z; r[7] = (__bf16)b.w;
    return r;
}

// out[b,m] = 0.9*mlp_b[m] + 0.1*fk_b[m]
__global__ void init_out(const float* __restrict__ mlp_b,
                         const float* __restrict__ fk_b,
                         float* __restrict__ out) {
    int i = blockIdx.x * 256 + threadIdx.x;
    if (i < B_ * M_) {
        int m = i % M_;
        out[i] = 0.9f * mlp_b[m] + 0.1f * fk_b[m];
    }
}

// A (sent_emb) f32 -> bf16, row-major copy. 16B/lane stores.
__global__ void cvt_a(const float* __restrict__ A, __bf16* __restrict__ Abf) {
    const int n8 = (B_ * KTOT) / 8;
    for (int i = blockIdx.x * blockDim.x + threadIdx.x; i < n8;
         i += gridDim.x * blockDim.x) {
        *(bf16x8*)(Abf + (size_t)i * 8) = cvt8(A + (size_t)i * 8);
    }
}

__global__ void event_pool(const float* __restrict__ SE,
                           const int* __restrict__ BE, int be_stride,
                           float* __restrict__ EP) {
    int b = blockIdx.x;
    int s1 = BE[(b*4 + 0) * be_stride];
    int e1 = BE[(b*4 + 1) * be_stride];
    int s2 = BE[(b*4 + 2) * be_stride];
    int e2 = BE[(b*4 + 3) * be_stride];
    float inv1 = 1.0f / (float)(e1 - s1);
    float inv2 = 1.0f / (float)(e2 - s2);
    for (int c = threadIdx.x; c < E_; c += 256) {
        float sum1 = 0.f, sum2 = 0.f;
        for (int s = s1; s < e1; ++s) sum1 += SE[((size_t)b * S_ + s) * E_ + c];
        for (int s = s2; s < e2; ++s) sum2 += SE[((size_t)b * S_ + s) * E_ + c];
        EP[b * (2*E_) + c]       = sum1 * inv1;
        EP[b * (2*E_) + E_ + c]  = sum2 * inv2;
    }
}

// out[b,m] += 0.9 * dot(EP[b,:], mlp_w[m,:])   K=1536, one wave per 16x16 tile
__global__ __launch_bounds__(256) void mlp_gemm(const float* __restrict__ EP,
                                                const float* __restrict__ Wm,
                                                float* __restrict__ out) {
    const int wid   = (blockIdx.x * 256 + threadIdx.x) >> 6;  // 0..383
    const int lane  = threadIdx.x & 63;
    const int bt    = wid & 7;    // b-tile 0..7
    const int mt    = wid >> 3;   // m-tile 0..47
    const int row16 = lane & 15;
    const int kgrp  = lane >> 4;
    const float* Arow = EP + (size_t)(bt*16 + row16) * (2*E_);
    const float* Brow = Wm + (size_t)(mt*16 + row16) * (2*E_);
    f32x4 acc = {};
    for (int k0 = 0; k0 < 2*E_; k0 += 32) {
        bf16x8 af = cvt8(Arow + k0 + kgrp*8);
        bf16x8 bv = cvt8(Brow + k0 + kgrp*8);
        acc = __builtin_amdgcn_mfma_f32_16x16x32_bf16(af, bv, acc, 0, 0, 0);
    }
    const int m = mt*16 + row16;
#pragma unroll
    for (int r = 0; r < 4; ++r) {
        const int b = bt*16 + kgrp*4 + r;
        out[b * M_ + m] += 0.9f * acc[r];  // unique writer per element in this kernel
    }
}

// partial[kz][b][m] = dot(Abf[b,kslice], W[m,kslice])
// Barrier-free streaming GEMM: one wave owns 128b x 16m. No LDS.
// Per 32-k step: 2 float4 W loads (HBM, read exactly once chip-wide),
// 8 bf16x8 A loads (L2/LLC-resident), 8 cvt, 8 MFMA. Depth-1 register
// prefetch on both streams; compiler emits counted vmcnt waits; no drains.
// XCD decode: each kz's 12 wgs (48 mt-waves) sit on one XCD for A L2 reuse.
__global__ __launch_bounds__(256) void fk_gemm(const __bf16* __restrict__ Abf,
                                               const float* __restrict__ W,
                                               float* __restrict__ partial) {
    const int wgid = blockIdx.x;        // 0..383
    const int xcd  = wgid & 7;
    const int slot = wgid >> 3;         // 0..47 per-XCD sequence
    const int kzg  = slot / 12;         // 0..3
    const int wsl  = slot % 12;         // 0..11
    const int kz   = xcd + 8 * kzg;     // 0..31
    const int wave = threadIdx.x >> 6;  // 0..3
    const int mt   = wsl * 4 + wave;    // 0..47
    const int lane  = threadIdx.x & 63;
    const int row16 = lane & 15;
    const int kgrp  = lane >> 4;

    const int kbase = kz * (STEPS * 32);
    const float*  wbase = W   + (size_t)(mt * 16 + row16) * KTOT + kbase + kgrp * 8;
    const __bf16* abase = Abf + (size_t)row16 * KTOT + kbase + kgrp * 8;

    f32x4 acc[8] = {};
    float4 wn0, wn1;
    bf16x8 an[8];

    // prologue: load step 0
    wn0 = *(const float4*)(wbase);
    wn1 = *(const float4*)(wbase + 4);
#pragma unroll
    for (int bt = 0; bt < 8; ++bt)
        an[bt] = *(const bf16x8*)(abase + (size_t)bt * 16 * KTOT);

    for (int s = 0; s < STEPS - 1; ++s) {
        float4 wc0 = wn0, wc1 = wn1;
        bf16x8 ac[8];
#pragma unroll
        for (int bt = 0; bt < 8; ++bt) ac[bt] = an[bt];

        // prefetch step s+1 (always in-bounds here)
        const float*  wp = wbase + (s + 1) * 32;
        const __bf16* ap = abase + (s + 1) * 32;
        wn0 = *(const float4*)(wp);
        wn1 = *(const float4*)(wp + 4);
#pragma unroll
        for (int bt = 0; bt < 8; ++bt)
            an[bt] = *(const bf16x8*)(ap + (size_t)bt * 16 * KTOT);

        bf16x8 wf = cvt8v(wc0, wc1);
#pragma unroll
        for (int bt = 0; bt < 8; ++bt)
            acc[bt] = __builtin_amdgcn_mfma_f32_16x16x32_bf16(ac[bt], wf, acc[bt], 0, 0, 0);
    }
    // epilogue: last step
    {
        bf16x8 wf = cvt8v(wn0, wn1);
#pragma unroll
        for (int bt = 0; bt < 8; ++bt)
            acc[bt] = __builtin_amdgcn_mfma_f32_16x16x32_bf16(an[bt], wf, acc[bt], 0, 0, 0);
    }

    // D layout: col(lane&15) = m, row((lane>>4)*4 + r) = b   [m89/m91]
    float* pz = partial + (size_t)kz * (B_ * M_);
    const int m = mt * 16 + row16;
#pragma unroll
    for (int bt = 0; bt < 8; ++bt) {
#pragma unroll
        for (int r = 0; r < 4; ++r) {
            const int b = bt * 16 + kgrp * 4 + r;
            pz[(size_t)b * M_ + m] = acc[bt][r];
        }
    }
}

// out[i] += 0.1 * sum_kz partial[kz][i], z split into ZC chunks via atomics
__global__ void reduce_k(const float* __restrict__ pp, float* __restrict__ out) {
    int t = blockIdx.x * 256 + threadIdx.x;
    int i = t % (B_ * M_);
    int zc = t / (B_ * M_);
    if (zc >= ZC) return;
    float s = 0.f;
#pragma unroll
    for (int z = zc * (KSPLIT / ZC); z < (zc + 1) * (KSPLIT / ZC); ++z)
        s += pp[(size_t)z * (B_ * M_) + i];
    atomicAdd(out + i, 0.1f * s);
}

extern "C" void kernel_launch(void* const* d_in, const int* in_sizes, int n_in,
                              void* d_out, int out_size, void* d_ws, size_t ws_size,
                              hipStream_t stream) {
    const float* se    = (const float*)d_in[0];
    const int*   be    = (const int*)  d_in[1];
    const float* mlp_w = (const float*)d_in[2];
    const float* mlp_b = (const float*)d_in[3];
    const float* fk_w  = (const float*)d_in[4];
    const float* fk_b  = (const float*)d_in[5];
    float* out = (float*)d_out;
    float* ep  = (float*)d_ws;                  // event_pair [128][1536] f32
    float* pp  = ep + (size_t)B_ * 2 * E_;      // partials [KSPLIT][128][768] f32
    __bf16* abf = (__bf16*)(pp + (size_t)KSPLIT * B_ * M_);  // A bf16 [128][150528]

    const int be_stride = (in_sizes[1] == B_ * 4 * 2) ? 2 : 1;

    init_out<<<(B_ * M_ + 255) / 256, 256, 0, stream>>>(mlp_b, fk_b, out);
    cvt_a<<<2048, 256, 0, stream>>>(se, abf);
    event_pool<<<B_, 256, 0, stream>>>(se, be, be_stride, ep);
    mlp_gemm<<<(B_ / 16) * (M_ / 16) / 4, 256, 0, stream>>>(ep, mlp_w, out);
    fk_gemm<<<(M_ / 16) * KSPLIT / 4, 256, 0, stream>>>(abf, fk_w, pp);
    reduce_k<<<(B_ * M_ * ZC + 255) / 256, 256, 0, stream>>>(pp, out);
}

// Round 7
// 391.275 us; speedup vs baseline: 1.1535x; 1.1535x over previous
//
#include <hip/hip_runtime.h>
#include <hip/hip_bf16.h>

#define B_ 128
#define S_ 196
#define E_ 768
#define M_ 768
#define KTOT (S_*E_)      // 150528
#define KSPLIT 96
#define KSLICE (KTOT/KSPLIT)  // 1568
#define STEPS (KSLICE/32)     // 49
#define ZC 4              // z-chunks in reduce kernel

typedef __bf16 bf16x8 __attribute__((ext_vector_type(8)));
typedef float  f32x4  __attribute__((ext_vector_type(4)));

__device__ inline bf16x8 cvt8(const float* __restrict__ p) {
    float4 a = *(const float4*)p;
    float4 b = *(const float4*)(p + 4);
    bf16x8 r;
    r[0] = (__bf16)a.x; r[1] = (__bf16)a.y; r[2] = (__bf16)a.z; r[3] = (__bf16)a.w;
    r[4] = (__bf16)b.x; r[5] = (__bf16)b.y; r[6] = (__bf16)b.z; r[7] = (__bf16)b.w;
    return r;
}

__device__ inline bf16x8 cvt8v(float4 a, float4 b) {
    bf16x8 r;
    r[0] = (__bf16)a.x; r[1] = (__bf16)a.y; r[2] = (__bf16)a.z; r[3] = (__bf16)a.w;
    r[4] = (__bf16)b.x; r[5] = (__bf16)b.y; r[6] = (__bf16)b.z; r[7] = (__bf16)b.w;
    return r;
}

// out[b,m] = 0.9*mlp_b[m] + 0.1*fk_b[m]
__global__ void init_out(const float* __restrict__ mlp_b,
                         const float* __restrict__ fk_b,
                         float* __restrict__ out) {
    int i = blockIdx.x * 256 + threadIdx.x;
    if (i < B_ * M_) {
        int m = i % M_;
        out[i] = 0.9f * mlp_b[m] + 0.1f * fk_b[m];
    }
}

// A (sent_emb) f32 -> bf16, row-major copy. 16B/lane stores.
__global__ void cvt_a(const float* __restrict__ A, __bf16* __restrict__ Abf) {
    const int n8 = (B_ * KTOT) / 8;
    for (int i = blockIdx.x * blockDim.x + threadIdx.x; i < n8;
         i += gridDim.x * blockDim.x) {
        *(bf16x8*)(Abf + (size_t)i * 8) = cvt8(A + (size_t)i * 8);
    }
}

__global__ void event_pool(const float* __restrict__ SE,
                           const int* __restrict__ BE, int be_stride,
                           float* __restrict__ EP) {
    int b = blockIdx.x;
    int s1 = BE[(b*4 + 0) * be_stride];
    int e1 = BE[(b*4 + 1) * be_stride];
    int s2 = BE[(b*4 + 2) * be_stride];
    int e2 = BE[(b*4 + 3) * be_stride];
    float inv1 = 1.0f / (float)(e1 - s1);
    float inv2 = 1.0f / (float)(e2 - s2);
    for (int c = threadIdx.x; c < E_; c += 256) {
        float sum1 = 0.f, sum2 = 0.f;
        for (int s = s1; s < e1; ++s) sum1 += SE[((size_t)b * S_ + s) * E_ + c];
        for (int s = s2; s < e2; ++s) sum2 += SE[((size_t)b * S_ + s) * E_ + c];
        EP[b * (2*E_) + c]       = sum1 * inv1;
        EP[b * (2*E_) + E_ + c]  = sum2 * inv2;
    }
}

// out[b,m] += 0.9 * dot(EP[b,:], mlp_w[m,:])   K=1536, one wave per 16x16 tile
__global__ __launch_bounds__(256) void mlp_gemm(const float* __restrict__ EP,
                                                const float* __restrict__ Wm,
                                                float* __restrict__ out) {
    const int wid   = (blockIdx.x * 256 + threadIdx.x) >> 6;  // 0..383
    const int lane  = threadIdx.x & 63;
    const int bt    = wid & 7;    // b-tile 0..7
    const int mt    = wid >> 3;   // m-tile 0..47
    const int row16 = lane & 15;
    const int kgrp  = lane >> 4;
    const float* Arow = EP + (size_t)(bt*16 + row16) * (2*E_);
    const float* Brow = Wm + (size_t)(mt*16 + row16) * (2*E_);
    f32x4 acc = {};
    for (int k0 = 0; k0 < 2*E_; k0 += 32) {
        bf16x8 af = cvt8(Arow + k0 + kgrp*8);
        bf16x8 bv = cvt8(Brow + k0 + kgrp*8);
        acc = __builtin_amdgcn_mfma_f32_16x16x32_bf16(af, bv, acc, 0, 0, 0);
    }
    const int m = mt*16 + row16;
#pragma unroll
    for (int r = 0; r < 4; ++r) {
        const int b = bt*16 + kgrp*4 + r;
        out[b * M_ + m] += 0.9f * acc[r];  // unique writer per element in this kernel
    }
}

// partial[kz][b][m] = dot(Abf[b,kslice], W[m,kslice])
// Barrier-free streaming GEMM, one wave owns 128b x 16m x 1568k. No LDS.
// Per 32-k step: 2 float4 W loads (HBM, each W elem read once chip-wide),
// 8 bf16x8 A loads (L2-resident, 401 KB/kz slice). Unroll-2 software pipeline
// with two NAMED register sets (no copies, no runtime indexing) so the
// compiler keeps a full phase of load latency slack. 1152 wgs = 18 waves/CU.
#define LOADSTEP(WN0, WN1, AN, s)                                            \
    WN0 = *(const float4*)(wbase + (size_t)(s) * 32);                        \
    WN1 = *(const float4*)(wbase + (size_t)(s) * 32 + 4);                    \
    _Pragma("unroll")                                                        \
    for (int bt = 0; bt < 8; ++bt)                                           \
        AN[bt] = *(const bf16x8*)(abase + (size_t)bt * 16 * KTOT + (size_t)(s) * 32);

#define COMPUTESTEP(WN0, WN1, AN) {                                          \
    bf16x8 wf = cvt8v(WN0, WN1);                                             \
    _Pragma("unroll")                                                        \
    for (int bt = 0; bt < 8; ++bt)                                           \
        acc[bt] = __builtin_amdgcn_mfma_f32_16x16x32_bf16(AN[bt], wf, acc[bt], 0, 0, 0); }

__global__ __launch_bounds__(256) void fk_gemm(const __bf16* __restrict__ Abf,
                                               const float* __restrict__ W,
                                               float* __restrict__ partial) {
    const int wgid = blockIdx.x;        // 0..1151
    const int xcd  = wgid & 7;
    const int slot = wgid >> 3;         // 0..143 per-XCD sequence
    const int kzl  = slot / 12;         // 0..11
    const int wsl  = slot % 12;         // 0..11
    const int kz   = xcd + 8 * kzl;     // 0..95
    const int wave = threadIdx.x >> 6;  // 0..3
    const int mt   = wsl * 4 + wave;    // 0..47
    const int lane  = threadIdx.x & 63;
    const int row16 = lane & 15;
    const int kgrp  = lane >> 4;

    const int kbase = kz * KSLICE;
    const float*  wbase = W   + (size_t)(mt * 16 + row16) * KTOT + kbase + kgrp * 8;
    const __bf16* abase = Abf + (size_t)row16 * KTOT + kbase + kgrp * 8;

    f32x4 acc[8] = {};
    float4 wA0, wA1, wB0, wB1;
    bf16x8 aA[8], aB[8];

    // prologue: load step 0 into set A
    LOADSTEP(wA0, wA1, aA, 0)

    // 24 double-iterations cover steps 0..47; epilogue computes step 48
    for (int i = 0; i < (STEPS - 1) / 2; ++i) {
        LOADSTEP(wB0, wB1, aB, 2 * i + 1)
        COMPUTESTEP(wA0, wA1, aA)
        LOADSTEP(wA0, wA1, aA, 2 * i + 2)
        COMPUTESTEP(wB0, wB1, aB)
    }
    COMPUTESTEP(wA0, wA1, aA)

    // D layout: col(lane&15) = m, row((lane>>4)*4 + r) = b   [m89/m91]
    float* pz = partial + (size_t)kz * (B_ * M_);
    const int m = mt * 16 + row16;
#pragma unroll
    for (int bt = 0; bt < 8; ++bt) {
#pragma unroll
        for (int r = 0; r < 4; ++r) {
            const int b = bt * 16 + kgrp * 4 + r;
            pz[(size_t)b * M_ + m] = acc[bt][r];
        }
    }
}

// out[i] += 0.1 * sum_kz partial[kz][i], z split into ZC chunks via atomics
__global__ void reduce_k(const float* __restrict__ pp, float* __restrict__ out) {
    int t = blockIdx.x * 256 + threadIdx.x;
    int i = t % (B_ * M_);
    int zc = t / (B_ * M_);
    if (zc >= ZC) return;
    float s = 0.f;
#pragma unroll 4
    for (int z = zc * (KSPLIT / ZC); z < (zc + 1) * (KSPLIT / ZC); ++z)
        s += pp[(size_t)z * (B_ * M_) + i];
    atomicAdd(out + i, 0.1f * s);
}

extern "C" void kernel_launch(void* const* d_in, const int* in_sizes, int n_in,
                              void* d_out, int out_size, void* d_ws, size_t ws_size,
                              hipStream_t stream) {
    const float* se    = (const float*)d_in[0];
    const int*   be    = (const int*)  d_in[1];
    const float* mlp_w = (const float*)d_in[2];
    const float* mlp_b = (const float*)d_in[3];
    const float* fk_w  = (const float*)d_in[4];
    const float* fk_b  = (const float*)d_in[5];
    float* out = (float*)d_out;
    float* ep  = (float*)d_ws;                  // event_pair [128][1536] f32
    float* pp  = ep + (size_t)B_ * 2 * E_;      // partials [KSPLIT][128][768] f32
    __bf16* abf = (__bf16*)(pp + (size_t)KSPLIT * B_ * M_);  // A bf16 [128][150528]

    const int be_stride = (in_sizes[1] == B_ * 4 * 2) ? 2 : 1;

    init_out<<<(B_ * M_ + 255) / 256, 256, 0, stream>>>(mlp_b, fk_b, out);
    cvt_a<<<2048, 256, 0, stream>>>(se, abf);
    event_pool<<<B_, 256, 0, stream>>>(se, be, be_stride, ep);
    mlp_gemm<<<(B_ / 16) * (M_ / 16) / 4, 256, 0, stream>>>(ep, mlp_w, out);
    fk_gemm<<<(M_ / 16) * KSPLIT / 4, 256, 0, stream>>>(abf, fk_w, pp);
    reduce_k<<<(B_ * M_ * ZC + 255) / 256, 256, 0, stream>>>(pp, out);
}

// Round 8
// 189.422 us; speedup vs baseline: 2.3828x; 2.0656x over previous
//
#include <hip/hip_runtime.h>
#include <hip/hip_bf16.h>

#define B_ 128
#define S_ 196
#define E_ 768
#define M_ 768
#define KTOT (S_*E_)            // 150528
#define BK 256                  // k per superstep
#define SS_TOTAL (KTOT/BK)      // 588
#define KSPLIT 42
#define SS_PER (SS_TOTAL/KSPLIT) // 14
#define BN 48                   // m-rows per workgroup
#define MTN (M_/BN)             // 16
#define PITCH 528               // LDS row pitch bytes (512 + 16 pad -> 2-way banks)
#define ZC 6                    // z-chunks in reduce kernel

typedef __bf16 bf16x8 __attribute__((ext_vector_type(8)));
typedef __bf16 bf16x4 __attribute__((ext_vector_type(4)));
typedef float  f32x4  __attribute__((ext_vector_type(4)));

__device__ inline bf16x8 cvt8(const float* __restrict__ p) {
    float4 a = *(const float4*)p;
    float4 b = *(const float4*)(p + 4);
    bf16x8 r;
    r[0] = (__bf16)a.x; r[1] = (__bf16)a.y; r[2] = (__bf16)a.z; r[3] = (__bf16)a.w;
    r[4] = (__bf16)b.x; r[5] = (__bf16)b.y; r[6] = (__bf16)b.z; r[7] = (__bf16)b.w;
    return r;
}

// out[b,m] = 0.9*mlp_b[m] + 0.1*fk_b[m]
__global__ void init_out(const float* __restrict__ mlp_b,
                         const float* __restrict__ fk_b,
                         float* __restrict__ out) {
    int i = blockIdx.x * 256 + threadIdx.x;
    if (i < B_ * M_) {
        int m = i % M_;
        out[i] = 0.9f * mlp_b[m] + 0.1f * fk_b[m];
    }
}

// Pack A (f32 row-major) into MFMA fragment order, bf16:
// Apk element offset ((ss*8 + bt)*8 + kf)*512 + lane*8 holds
// A[bt*16 + (lane&15)][ss*256 + kf*32 + (lane>>4)*8 .. +8).
// Writes fully coalesced; reads are 32B/thread from LLC-resident A.
__global__ void pack_a(const float* __restrict__ A, __bf16* __restrict__ Apk) {
    const int nchunk = SS_TOTAL * 8 * 8 * 64;   // 2,408,448 chunks of 8 elems
    for (int c = blockIdx.x * blockDim.x + threadIdx.x; c < nchunk;
         c += gridDim.x * blockDim.x) {
        int lane = c & 63;
        int kf   = (c >> 6) & 7;
        int bt   = (c >> 9) & 7;
        int ss   = c >> 12;
        int b = bt * 16 + (lane & 15);
        int k = ss * BK + kf * 32 + (lane >> 4) * 8;
        *(bf16x8*)(Apk + (size_t)c * 8) = cvt8(A + (size_t)b * KTOT + k);
    }
}

__global__ void event_pool(const float* __restrict__ SE,
                           const int* __restrict__ BE, int be_stride,
                           float* __restrict__ EP) {
    int b = blockIdx.x;
    int s1 = BE[(b*4 + 0) * be_stride];
    int e1 = BE[(b*4 + 1) * be_stride];
    int s2 = BE[(b*4 + 2) * be_stride];
    int e2 = BE[(b*4 + 3) * be_stride];
    float inv1 = 1.0f / (float)(e1 - s1);
    float inv2 = 1.0f / (float)(e2 - s2);
    for (int c = threadIdx.x; c < E_; c += 256) {
        float sum1 = 0.f, sum2 = 0.f;
        for (int s = s1; s < e1; ++s) sum1 += SE[((size_t)b * S_ + s) * E_ + c];
        for (int s = s2; s < e2; ++s) sum2 += SE[((size_t)b * S_ + s) * E_ + c];
        EP[b * (2*E_) + c]       = sum1 * inv1;
        EP[b * (2*E_) + E_ + c]  = sum2 * inv2;
    }
}

// out[b,m] += 0.9 * dot(EP[b,:], mlp_w[m,:])   K=1536, one wave per 16x16 tile
__global__ __launch_bounds__(256) void mlp_gemm(const float* __restrict__ EP,
                                                const float* __restrict__ Wm,
                                                float* __restrict__ out) {
    const int wid   = (blockIdx.x * 256 + threadIdx.x) >> 6;  // 0..383
    const int lane  = threadIdx.x & 63;
    const int bt    = wid & 7;    // b-tile 0..7
    const int mt    = wid >> 3;   // m-tile 0..47
    const int row16 = lane & 15;
    const int kgrp  = lane >> 4;
    const float* Arow = EP + (size_t)(bt*16 + row16) * (2*E_);
    const float* Brow = Wm + (size_t)(mt*16 + row16) * (2*E_);
    f32x4 acc = {};
    for (int k0 = 0; k0 < 2*E_; k0 += 32) {
        bf16x8 af = cvt8(Arow + k0 + kgrp*8);
        bf16x8 bv = cvt8(Brow + k0 + kgrp*8);
        acc = __builtin_amdgcn_mfma_f32_16x16x32_bf16(af, bv, acc, 0, 0, 0);
    }
    const int m = mt*16 + row16;
#pragma unroll
    for (int r = 0; r < 4; ++r) {
        const int b = bt*16 + kgrp*4 + r;
        out[b * M_ + m] += 0.9f * acc[r];  // unique writer per element in this kernel
    }
}

// partial[kz][b][m] = dot(A[b,kslice], W[m,kslice])
// 8 waves, tile 128b x 48m x 256k/superstep. EVERY global load is one
// contiguous segment: A register-direct from packed fragments (1KB/load),
// W staged via 1KB-per-row wave loads -> f32->bf16 -> LDS (pitch 528 B,
// 2-way banks on ds_read_b128). Double-buffered LDS, depth-1 named-set A
// prefetch, one barrier per superstep. 672 wgs, 2 wg/CU.

#define LOAD_A(AREG, sl)                                                      \
    _Pragma("unroll")                                                         \
    for (int kf = 0; kf < 8; ++kf)                                            \
        AREG[kf] = *(const bf16x8*)(abase + (size_t)(sl) * 32768 + kf * 512);

#define LOAD_W(sl)                                                            \
    _Pragma("unroll")                                                         \
    for (int i = 0; i < 6; ++i)                                               \
        wr[i] = *(const float4*)(wbase + (size_t)i * KTOT + (size_t)(sl) * BK);

#define WRITE_W(buf)                                                          \
    _Pragma("unroll")                                                         \
    for (int i = 0; i < 6; ++i) {                                             \
        bf16x4 h;                                                             \
        h[0] = (__bf16)wr[i].x; h[1] = (__bf16)wr[i].y;                       \
        h[2] = (__bf16)wr[i].z; h[3] = (__bf16)wr[i].w;                       \
        *(bf16x4*)(&Wlds[buf][0] + wb + i * PITCH) = h;                       \
    }

#define COMPUTE(AREG, buf)                                                    \
    _Pragma("unroll")                                                         \
    for (int kf = 0; kf < 8; ++kf) {                                          \
        _Pragma("unroll")                                                     \
        for (int n = 0; n < 3; ++n) {                                         \
            bf16x8 wf = *(const bf16x8*)(&Wlds[buf][0] +                      \
                        (n * 16 + r16) * PITCH + kf * 64 + kg * 16);          \
            acc[n] = __builtin_amdgcn_mfma_f32_16x16x32_bf16(AREG[kf], wf,    \
                                                             acc[n], 0, 0, 0);\
        }                                                                     \
    }

__global__ __launch_bounds__(512, 4) void fk_gemm(const __bf16* __restrict__ Apk,
                                                  const float* __restrict__ W,
                                                  float* __restrict__ partial) {
    __shared__ __align__(16) char Wlds[2][BN * PITCH];  // 2 x 25,344 B

    const int wg = blockIdx.x;          // 0..671
    const int mt = wg % MTN;            // 0..15
    const int kz = wg / MTN;            // 0..41
    const int ss0 = kz * SS_PER;

    const int tid = threadIdx.x;
    const int wv  = tid >> 6;           // 0..7 = b-tile
    const int lane = tid & 63;
    const int r16 = lane & 15;
    const int kg  = lane >> 4;

    const float*  wbase = W + (size_t)(mt * BN + wv * 6) * KTOT
                            + (size_t)ss0 * BK + lane * 4;
    const int     wb    = (wv * 6) * PITCH + lane * 8;
    const __bf16* abase = Apk + ((size_t)ss0 * 8 + wv) * 4096 + lane * 8;

    f32x4 acc[3] = {};
    float4 wr[6];
    bf16x8 aA[8], aB[8];

    // prologue: stage ss-local 0 into buf 0
    LOAD_W(0)
    LOAD_A(aA, 0)
    WRITE_W(0)
    __syncthreads();

#pragma unroll
    for (int p = 0; p < SS_PER / 2; ++p) {
        // ss = 2p  (buf 0)
        LOAD_W(2 * p + 1)
        LOAD_A(aB, 2 * p + 1)
        COMPUTE(aA, 0)
        WRITE_W(1)
        __syncthreads();
        // ss = 2p+1  (buf 1)
        if (p < SS_PER / 2 - 1) {
            LOAD_W(2 * p + 2)
            LOAD_A(aA, 2 * p + 2)
        }
        COMPUTE(aB, 1)
        if (p < SS_PER / 2 - 1) {
            WRITE_W(0)
        }
        __syncthreads();
    }

    // D layout: col(lane&15) = m, row((lane>>4)*4 + r) = b   [m89/m91]
    float* pz = partial + (size_t)kz * (B_ * M_);
#pragma unroll
    for (int n = 0; n < 3; ++n) {
        const int m = mt * BN + n * 16 + r16;
#pragma unroll
        for (int r = 0; r < 4; ++r) {
            const int b = wv * 16 + kg * 4 + r;
            pz[(size_t)b * M_ + m] = acc[n][r];
        }
    }
}

// out[i] += 0.1 * sum_kz partial[kz][i], z split into ZC chunks via atomics
__global__ void reduce_k(const float* __restrict__ pp, float* __restrict__ out) {
    int t = blockIdx.x * 256 + threadIdx.x;
    int i = t % (B_ * M_);
    int zc = t / (B_ * M_);
    if (zc >= ZC) return;
    float s = 0.f;
#pragma unroll
    for (int z = zc * (KSPLIT / ZC); z < (zc + 1) * (KSPLIT / ZC); ++z)
        s += pp[(size_t)z * (B_ * M_) + i];
    atomicAdd(out + i, 0.1f * s);
}

extern "C" void kernel_launch(void* const* d_in, const int* in_sizes, int n_in,
                              void* d_out, int out_size, void* d_ws, size_t ws_size,
                              hipStream_t stream) {
    const float* se    = (const float*)d_in[0];
    const int*   be    = (const int*)  d_in[1];
    const float* mlp_w = (const float*)d_in[2];
    const float* mlp_b = (const float*)d_in[3];
    const float* fk_w  = (const float*)d_in[4];
    const float* fk_b  = (const float*)d_in[5];
    float* out = (float*)d_out;
    float* ep  = (float*)d_ws;                  // event_pair [128][1536] f32
    float* pp  = ep + (size_t)B_ * 2 * E_;      // partials [KSPLIT][128][768] f32
    __bf16* apk = (__bf16*)(pp + (size_t)KSPLIT * B_ * M_);  // packed A bf16

    const int be_stride = (in_sizes[1] == B_ * 4 * 2) ? 2 : 1;

    init_out<<<(B_ * M_ + 255) / 256, 256, 0, stream>>>(mlp_b, fk_b, out);
    pack_a<<<3072, 256, 0, stream>>>(se, apk);
    event_pool<<<B_, 256, 0, stream>>>(se, be, be_stride, ep);
    mlp_gemm<<<(B_ / 16) * (M_ / 16) / 4, 256, 0, stream>>>(ep, mlp_w, out);
    fk_gemm<<<MTN * KSPLIT, 512, 0, stream>>>(apk, fk_w, pp);
    reduce_k<<<(B_ * M_ * ZC + 255) / 256, 256, 0, stream>>>(pp, out);
}